// Round 7
// baseline (320.043 us; speedup 1.0000x reference)
//
#include <hip/hip_runtime.h>
#include <hip/hip_bf16.h>

// ClauseExtractor: B=8,S=512,D=256,MAX_SPAN=100,NUM_TYPES=15, N spans=46250.
// h_pre[b,(s,e)] = P[b,s] + Q[b,e],  P=E@Wenc[:256]+b_enc, Q=E@Wenc[256:]  (bf16 PQ)
// k2 rev6: L2-traffic cut. rev5 showed occupancy is NOT resource-capped
// (44 VGPR/32KB LDS allow 4-5 blocks/CU, measured 41%) — kernel is bound by
// redundant L2 streams: every block re-read the full 128KB WT (740 MB/disp).
// Now 4 batches per block (grid 723x2): WT traffic /4, width frags + biases
// hoisted to regs (batch-invariant). 4 barriers/batch. No cross-batch reg
// prefetch (vmcnt ordered-drain, rev3 lesson).

#define B_ 8
#define S_ 512
#define D_ 256
#define NSPANS 46250
#define NTILES 723  // ceil(46250/64)

typedef __bf16 bf16x8 __attribute__((ext_vector_type(8)));
typedef __bf16 bf16x4 __attribute__((ext_vector_type(4)));
typedef float float4_ __attribute__((ext_vector_type(4)));

#define MFMA16(a, b, c) __builtin_amdgcn_mfma_f32_16x16x32_bf16((a), (b), (c), 0, 0, 0)

// ---- workspace layout (bytes) ----
#define WS_STARTS 0u
#define WS_ENDS 185344u
#define WS_WENCP 370688u   // bf16[32][512][8]  = 262144
#define WS_WT 632832u      // bf16[32][256][8]  = 131072
#define WS_GT 763904u      // bf16[32][16][8]   = 8192
#define WS_BSC 772096u     // f32[256]
#define WS_GB 773120u      // f32[16]
#define WS_WTB 773184u     // bf16[100][256]    = 51200
#define WS_PQ 824384u      // bf16[4096][512]   = 4194304
#define WS_NEED (WS_PQ + 4194304u)

__device__ __forceinline__ unsigned hswz(int row, unsigned byteInRow) {
  // XOR-swizzle: spreads 16-row column slices across 8 distinct 16B slots (G4)
  return (unsigned)row * 512u + (byteInRow ^ (((unsigned)row & 7u) << 4));
}

// ---------- kernel 0: span meta + weight repack (merged) ----------
__global__ void k0_pack(const float* __restrict__ Wenc, const float* __restrict__ Ws1,
                        const float* __restrict__ Wc1, const float* __restrict__ Ws2,
                        const float* __restrict__ Wc2, const float* __restrict__ bs1,
                        const float* __restrict__ bc1, const float* __restrict__ bs2,
                        const float* __restrict__ bc2, const float* __restrict__ wtab,
                        __bf16* __restrict__ WencP, __bf16* __restrict__ WT,
                        __bf16* __restrict__ GT, float* __restrict__ bsc,
                        float* __restrict__ gbv, __bf16* __restrict__ WTB,
                        int* __restrict__ starts, int* __restrict__ ends) {
  int idx = blockIdx.x * 256 + threadIdx.x;
  if (idx < 131072) {  // WencP[kc][n(512)][j]
    int j = idx & 7, n = (idx >> 3) & 511, kc = idx >> 12;
    int k = kc * 8 + j;
    float v = (n < 256) ? Wenc[k * 256 + n] : Wenc[(256 + k) * 256 + (n - 256)];
    WencP[idx] = (__bf16)v;
  }
  int i2 = idx - 131072;  // WT[kc][c(256)][j]
  if (i2 >= 0 && i2 < 65536) {
    int j = i2 & 7, c = (i2 >> 3) & 255, kc = i2 >> 11;
    int k = kc * 8 + j;
    float v = (c < 128) ? Ws1[k * 128 + c] : Wc1[k * 128 + (c - 128)];
    WT[i2] = (__bf16)v;
  }
  int i3 = idx - (131072 + 65536);  // GT[kc][c(16)][j]
  if (i3 >= 0 && i3 < 4096) {
    int j = i3 & 7, c = (i3 >> 3) & 15, kc = i3 >> 7;
    int k = kc * 8 + j;
    float v = 0.f;
    if (c == 0) { if (k < 128) v = Ws2[k]; }
    else { if (k >= 128) v = Wc2[(k - 128) * 15 + (c - 1)]; }
    GT[i3] = (__bf16)v;
  }
  int i4 = idx - (131072 + 65536 + 4096);
  if (i4 >= 0 && i4 < 256) bsc[i4] = (i4 < 128) ? bs1[i4] : bc1[i4 - 128];
  if (i4 >= 256 && i4 < 272) { int c = i4 - 256; gbv[c] = (c == 0) ? bs2[0] : bc2[c - 1]; }
  int i5 = idx - (131072 + 65536 + 4096 + 272);  // width table -> bf16
  if (i5 >= 0 && i5 < 25600) WTB[i5] = (__bf16)wtab[i5];
  int mi = idx - (131072 + 65536 + 4096 + 272 + 25600);  // span meta
  if (mi >= 0 && mi < 65536) {
    int i = mi >> 7, j = mi & 127;
    int len = min(100, S_ - i);
    if (j < len) {
      int cum;
      if (i <= 413) cum = 100 * i;
      else { int a = i - 413; cum = 41300 + 99 * a - (a * (a - 1)) / 2; }
      starts[cum + j] = i;
      ends[cum + j] = i + j;
    }
  }
}

// ---------- kernel 1: PQ = E @ [Wenc_P | Wenc_Q]  (M=4096,N=512,K=256), bf16 out ----------
__global__ __launch_bounds__(256) void k1_pq(const float* __restrict__ E,
                                             const __bf16* __restrict__ WencP,
                                             const float* __restrict__ benc,
                                             __bf16* __restrict__ PQ) {
  __shared__ float lds_f[64 * 66];  // padded (+2 f32) to break bank stride
  const int tid = threadIdx.x;
  const int w = tid >> 6, lane = tid & 63, llo = lane & 15, lhi = lane >> 4;
  const int mbase = blockIdx.x * 64 + w * 16;
  const int nbase = blockIdx.y * 64;
  const float* aptr = E + (size_t)(mbase + llo) * 256 + lhi * 8;
  float4_ acc[4];
#pragma unroll
  for (int tn = 0; tn < 4; tn++) acc[tn] = (float4_){0.f, 0.f, 0.f, 0.f};
#pragma unroll
  for (int ks = 0; ks < 8; ++ks) {
    float4_ e0 = *(const float4_*)(aptr + ks * 32);
    float4_ e1 = *(const float4_*)(aptr + ks * 32 + 4);
    bf16x8 af;
#pragma unroll
    for (int j = 0; j < 4; j++) { af[j] = (__bf16)e0[j]; af[4 + j] = (__bf16)e1[j]; }
#pragma unroll
    for (int tn = 0; tn < 4; tn++) {
      bf16x8 bfr = *(const bf16x8*)(WencP + ((ks * 4 + lhi) * 512 + nbase + tn * 16 + llo) * 8);
      acc[tn] = MFMA16(af, bfr, acc[tn]);
    }
  }
  // stage through LDS for coalesced bf16 stores
#pragma unroll
  for (int tn = 0; tn < 4; tn++) {
    int col = tn * 16 + llo;
    int gcol = nbase + col;
    float bb = (gcol < 256) ? benc[gcol] : 0.f;  // fold b_enc into P half
#pragma unroll
    for (int r = 0; r < 4; r++) lds_f[(w * 16 + lhi * 4 + r) * 66 + col] = acc[tn][r] + bb;
  }
  __syncthreads();
  {
    const int row = tid >> 2, seg = tid & 3;
    const float* src = lds_f + row * 66 + seg * 16;
    bf16x8 o0, o1;
#pragma unroll
    for (int j = 0; j < 8; j++) { o0[j] = (__bf16)src[j]; o1[j] = (__bf16)src[8 + j]; }
    size_t base = (size_t)(blockIdx.x * 64 + row) * 512 + nbase + seg * 16;
    *(bf16x8*)(PQ + base) = o0;
    *(bf16x8*)(PQ + base + 8) = o1;
  }
}

// ---------- kernel 2: fused span head — 8 waves, 4 batches per block ----------
__global__ __launch_bounds__(512, 4) void k2_main(
    const __bf16* __restrict__ PQ, const int* __restrict__ starts, const int* __restrict__ ends,
    const __bf16* __restrict__ WTB, const __bf16* __restrict__ WT, const __bf16* __restrict__ GT,
    const float* __restrict__ bsc, const float* __restrict__ gbv,
    float* __restrict__ outS, float* __restrict__ outL) {
  __shared__ __align__(16) unsigned char h_lds[32768];  // [64][256] bf16 swizzled; reused for sc
  const int tile = blockIdx.x;
  const int bbase = blockIdx.y * 4;
  const int tid = threadIdx.x;
  const int w = tid >> 6, lane = tid & 63, llo = lane & 15, lhi = lane >> 4;

  // ---- batch-invariant hoists: gather offsets, width frags, biases ----
  const int rowbase = tid >> 5;  // 0..15 (row = i*16 + rowbase)
  const int ch = tid & 31;       // 16B chunk within row
  const int col = (ch ^ (rowbase & 7)) * 8;  // LDS swizzle folded into gather col
  int offP[4], offQ[4];
  bf16x8 wv[4];
#pragma unroll
  for (int i = 0; i < 4; i++) {
    int span = tile * 64 + i * 16 + rowbase;
    span = min(span, NSPANS - 1);  // tail rows: compute a real span, masked at store
    int s = starts[span], e = ends[span];
    offP[i] = s * 512 + col;
    offQ[i] = e * 512 + 256 + col;
    wv[i] = *(const bf16x8*)(WTB + (e - s) * 256 + col);
  }
  float4_ bq[2];
#pragma unroll
  for (int tm = 0; tm < 2; tm++) bq[tm] = *(const float4_*)(bsc + w * 32 + tm * 16 + lhi * 4);
  const float4_ gq = *(const float4_*)(gbv + lhi * 4);

  for (int bi = 0; bi < 4; bi++) {
    const int b = bbase + bi;
    const __bf16* PQb = PQ + (size_t)b * (S_ * 512);

    // ---- stage 1: h = relu(P[s]+Q[e]) + width[e-s] -> bf16 LDS (linear writes) ----
    {
      bf16x8 pv[4], qv[4];
#pragma unroll
      for (int i = 0; i < 4; i++) {
        pv[i] = *(const bf16x8*)(PQb + offP[i]);
        qv[i] = *(const bf16x8*)(PQb + offQ[i]);
      }
#pragma unroll
      for (int i = 0; i < 4; i++) {
        bf16x8 hv;
#pragma unroll
        for (int j = 0; j < 8; j++)
          hv[j] = (__bf16)(fmaxf((float)pv[i][j] + (float)qv[i][j], 0.f) + (float)wv[i][j]);
        *(bf16x8*)(h_lds + (i * 512 + tid) * 16) = hv;
      }
    }
    __syncthreads();  // B1: h visible

    // ---- stage 2: D1^T[scCol][span] = sum_k Wsc[k][scCol]*h[span][k]; wave w: cols [32w,32w+32)
    float4_ acc[2][4];
#pragma unroll
    for (int tm = 0; tm < 2; tm++)
#pragma unroll
      for (int tn = 0; tn < 4; tn++) acc[tm][tn] = (float4_){0.f, 0.f, 0.f, 0.f};
#pragma unroll
    for (int ks = 0; ks < 8; ++ks) {
      bf16x8 af[2], bfr[4];
#pragma unroll
      for (int tm = 0; tm < 2; tm++)
        af[tm] = *(const bf16x8*)(WT + ((ks * 4 + lhi) * 256 + w * 32 + tm * 16 + llo) * 8);
#pragma unroll
      for (int tn = 0; tn < 4; tn++)
        bfr[tn] = *(const bf16x8*)(h_lds + hswz(tn * 16 + llo, (unsigned)(ks * 64 + lhi * 16)));
#pragma unroll
      for (int tm = 0; tm < 2; tm++)
#pragma unroll
        for (int tn = 0; tn < 4; tn++) acc[tm][tn] = MFMA16(af[tm], bfr[tn], acc[tm][tn]);
    }
    __syncthreads();  // B2: all h reads done before overwriting LDS with sc

    // epilogue: sc = relu(acc + bsc) -> h_lds (reuse)
#pragma unroll
    for (int tm = 0; tm < 2; tm++) {
#pragma unroll
      for (int tn = 0; tn < 4; tn++) {
        bf16x4 x;
#pragma unroll
        for (int r = 0; r < 4; r++) x[r] = (__bf16)fmaxf(acc[tm][tn][r] + bq[tm][r], 0.f);
        *(bf16x4*)(h_lds + hswz(tn * 16 + llo, (unsigned)((w * 32 + tm * 16 + lhi * 4) * 2))) = x;
      }
    }
    __syncthreads();  // B3: sc visible

    // ---- stage 3: D2^T[gcol][span] = sum_k G[k][gcol]*sc[span][k]; waves 0-3, 16 rows each
    if (w < 4) {
      float4_ a2 = (float4_){0.f, 0.f, 0.f, 0.f};
#pragma unroll
      for (int ks = 0; ks < 8; ++ks) {
        bf16x8 ga = *(const bf16x8*)(GT + ((ks * 4 + lhi) * 16 + llo) * 8);
        bf16x8 sb = *(const bf16x8*)(h_lds + hswz(w * 16 + llo, (unsigned)(ks * 64 + lhi * 16)));
        a2 = MFMA16(ga, sb, a2);
      }
      const int span2 = tile * 64 + w * 16 + llo;
      if (span2 < NSPANS) {
        size_t base = (size_t)b * NSPANS + span2;
#pragma unroll
        for (int r = 0; r < 4; r++) {
          float v = a2[r] + gq[r];
          int gcol = lhi * 4 + r;
          if (gcol == 0) outS[base] = v;           // span_scores (B,N)
          else outL[base * 15 + (gcol - 1)] = v;   // type_logits (B,N,15)
        }
      }
    }
    __syncthreads();  // B4: sc reads done before next batch overwrites h_lds
  }
}

extern "C" void kernel_launch(void* const* d_in, const int* in_sizes, int n_in,
                              void* d_out, int out_size, void* d_ws, size_t ws_size,
                              hipStream_t stream) {
  if (ws_size < (size_t)WS_NEED) return;  // need ~5.0 MB scratch
  const float* E = (const float*)d_in[0];
  const float* Wenc = (const float*)d_in[1];
  const float* benc = (const float*)d_in[2];
  const float* wtab = (const float*)d_in[3];
  const float* Ws1 = (const float*)d_in[4];
  const float* bs1 = (const float*)d_in[5];
  const float* Ws2 = (const float*)d_in[6];
  const float* bs2 = (const float*)d_in[7];
  const float* Wc1 = (const float*)d_in[8];
  const float* bc1 = (const float*)d_in[9];
  const float* Wc2 = (const float*)d_in[10];
  const float* bc2 = (const float*)d_in[11];

  unsigned char* ws = (unsigned char*)d_ws;
  int* starts = (int*)(ws + WS_STARTS);
  int* ends = (int*)(ws + WS_ENDS);
  __bf16* WencP = (__bf16*)(ws + WS_WENCP);
  __bf16* WT = (__bf16*)(ws + WS_WT);
  __bf16* GT = (__bf16*)(ws + WS_GT);
  float* bsc = (float*)(ws + WS_BSC);
  float* gbv = (float*)(ws + WS_GB);
  __bf16* WTB = (__bf16*)(ws + WS_WTB);
  __bf16* PQ = (__bf16*)(ws + WS_PQ);

  float* outS = (float*)d_out;
  float* outL = outS + (size_t)B_ * NSPANS;

  k0_pack<<<dim3(1142), dim3(256), 0, stream>>>(Wenc, Ws1, Wc1, Ws2, Wc2, bs1, bc1, bs2, bc2,
                                                wtab, WencP, WT, GT, bsc, gbv, WTB, starts, ends);
  k1_pq<<<dim3(64, 8), dim3(256), 0, stream>>>(E, WencP, benc, PQ);
  k2_main<<<dim3(NTILES, 2), dim3(512), 0, stream>>>(PQ, starts, ends, WTB, WT, GT, bsc, gbv,
                                                     outS, outL);
}

// Round 8
// 157.142 us; speedup vs baseline: 2.0366x; 2.0366x over previous
//
#include <hip/hip_runtime.h>
#include <hip/hip_bf16.h>

// ClauseExtractor: B=8,S=512,D=256,MAX_SPAN=100,NUM_TYPES=15, N spans=46250.
// h_pre[b,(s,e)] = P[b,s] + Q[b,e],  P=E@Wenc[:256]+b_enc, Q=E@Wenc[256:]  (bf16 PQ)
// k2 rev7: revert to rev5 structure (rev6's 4-batch hoists spilled: 500MB
// scratch traffic — NOTHING may be held across the MFMA phases at 512 thr).
// New: k-major LDS layout [kc2=k/8][span ^ (kc2&7)][16B] for h and sc.
// The span-XOR sits in addr bits 4-6, ks/tn contributions are higher bits ->
// every stage-2/3 LDS access = base reg + imm offset (tn*256 + ks*4096),
// zero per-iter address VALU (rev5 recomputed hswz XORs per access, ~40% of
// its 47% VALUBusy) and all LDS ops at the b128 bank floor (rev5: 8.1M
// conflicts). Gather columns now plain ch*8 (no XOR) -> better coalescing.

#define B_ 8
#define S_ 512
#define D_ 256
#define NSPANS 46250
#define NTILES 723  // ceil(46250/64)

typedef __bf16 bf16x8 __attribute__((ext_vector_type(8)));
typedef __bf16 bf16x4 __attribute__((ext_vector_type(4)));
typedef float float4_ __attribute__((ext_vector_type(4)));

#define MFMA16(a, b, c) __builtin_amdgcn_mfma_f32_16x16x32_bf16((a), (b), (c), 0, 0, 0)

// ---- workspace layout (bytes) ----
#define WS_STARTS 0u
#define WS_ENDS 185344u
#define WS_WENCP 370688u   // bf16[32][512][8]  = 262144
#define WS_WT 632832u      // bf16[32][256][8]  = 131072
#define WS_GT 763904u      // bf16[32][16][8]   = 8192
#define WS_BSC 772096u     // f32[256]
#define WS_GB 773120u      // f32[16]
#define WS_WTB 773184u     // bf16[100][256]    = 51200
#define WS_PQ 824384u      // bf16[4096][512]   = 4194304
#define WS_NEED (WS_PQ + 4194304u)

// ---------- kernel 0: span meta + weight repack (merged) ----------
__global__ void k0_pack(const float* __restrict__ Wenc, const float* __restrict__ Ws1,
                        const float* __restrict__ Wc1, const float* __restrict__ Ws2,
                        const float* __restrict__ Wc2, const float* __restrict__ bs1,
                        const float* __restrict__ bc1, const float* __restrict__ bs2,
                        const float* __restrict__ bc2, const float* __restrict__ wtab,
                        __bf16* __restrict__ WencP, __bf16* __restrict__ WT,
                        __bf16* __restrict__ GT, float* __restrict__ bsc,
                        float* __restrict__ gbv, __bf16* __restrict__ WTB,
                        int* __restrict__ starts, int* __restrict__ ends) {
  int idx = blockIdx.x * 256 + threadIdx.x;
  if (idx < 131072) {  // WencP[kc][n(512)][j]
    int j = idx & 7, n = (idx >> 3) & 511, kc = idx >> 12;
    int k = kc * 8 + j;
    float v = (n < 256) ? Wenc[k * 256 + n] : Wenc[(256 + k) * 256 + (n - 256)];
    WencP[idx] = (__bf16)v;
  }
  int i2 = idx - 131072;  // WT[kc][c(256)][j]
  if (i2 >= 0 && i2 < 65536) {
    int j = i2 & 7, c = (i2 >> 3) & 255, kc = i2 >> 11;
    int k = kc * 8 + j;
    float v = (c < 128) ? Ws1[k * 128 + c] : Wc1[k * 128 + (c - 128)];
    WT[i2] = (__bf16)v;
  }
  int i3 = idx - (131072 + 65536);  // GT[kc][c(16)][j]
  if (i3 >= 0 && i3 < 4096) {
    int j = i3 & 7, c = (i3 >> 3) & 15, kc = i3 >> 7;
    int k = kc * 8 + j;
    float v = 0.f;
    if (c == 0) { if (k < 128) v = Ws2[k]; }
    else { if (k >= 128) v = Wc2[(k - 128) * 15 + (c - 1)]; }
    GT[i3] = (__bf16)v;
  }
  int i4 = idx - (131072 + 65536 + 4096);
  if (i4 >= 0 && i4 < 256) bsc[i4] = (i4 < 128) ? bs1[i4] : bc1[i4 - 128];
  if (i4 >= 256 && i4 < 272) { int c = i4 - 256; gbv[c] = (c == 0) ? bs2[0] : bc2[c - 1]; }
  int i5 = idx - (131072 + 65536 + 4096 + 272);  // width table -> bf16
  if (i5 >= 0 && i5 < 25600) WTB[i5] = (__bf16)wtab[i5];
  int mi = idx - (131072 + 65536 + 4096 + 272 + 25600);  // span meta
  if (mi >= 0 && mi < 65536) {
    int i = mi >> 7, j = mi & 127;
    int len = min(100, S_ - i);
    if (j < len) {
      int cum;
      if (i <= 413) cum = 100 * i;
      else { int a = i - 413; cum = 41300 + 99 * a - (a * (a - 1)) / 2; }
      starts[cum + j] = i;
      ends[cum + j] = i + j;
    }
  }
}

// ---------- kernel 1: PQ = E @ [Wenc_P | Wenc_Q]  (M=4096,N=512,K=256), bf16 out ----------
__global__ __launch_bounds__(256) void k1_pq(const float* __restrict__ E,
                                             const __bf16* __restrict__ WencP,
                                             const float* __restrict__ benc,
                                             __bf16* __restrict__ PQ) {
  __shared__ float lds_f[64 * 66];  // padded (+2 f32) to break bank stride
  const int tid = threadIdx.x;
  const int w = tid >> 6, lane = tid & 63, llo = lane & 15, lhi = lane >> 4;
  const int mbase = blockIdx.x * 64 + w * 16;
  const int nbase = blockIdx.y * 64;
  const float* aptr = E + (size_t)(mbase + llo) * 256 + lhi * 8;
  float4_ acc[4];
#pragma unroll
  for (int tn = 0; tn < 4; tn++) acc[tn] = (float4_){0.f, 0.f, 0.f, 0.f};
#pragma unroll
  for (int ks = 0; ks < 8; ++ks) {
    float4_ e0 = *(const float4_*)(aptr + ks * 32);
    float4_ e1 = *(const float4_*)(aptr + ks * 32 + 4);
    bf16x8 af;
#pragma unroll
    for (int j = 0; j < 4; j++) { af[j] = (__bf16)e0[j]; af[4 + j] = (__bf16)e1[j]; }
#pragma unroll
    for (int tn = 0; tn < 4; tn++) {
      bf16x8 bfr = *(const bf16x8*)(WencP + ((ks * 4 + lhi) * 512 + nbase + tn * 16 + llo) * 8);
      acc[tn] = MFMA16(af, bfr, acc[tn]);
    }
  }
  // stage through LDS for coalesced bf16 stores
#pragma unroll
  for (int tn = 0; tn < 4; tn++) {
    int col = tn * 16 + llo;
    int gcol = nbase + col;
    float bb = (gcol < 256) ? benc[gcol] : 0.f;  // fold b_enc into P half
#pragma unroll
    for (int r = 0; r < 4; r++) lds_f[(w * 16 + lhi * 4 + r) * 66 + col] = acc[tn][r] + bb;
  }
  __syncthreads();
  {
    const int row = tid >> 2, seg = tid & 3;
    const float* src = lds_f + row * 66 + seg * 16;
    bf16x8 o0, o1;
#pragma unroll
    for (int j = 0; j < 8; j++) { o0[j] = (__bf16)src[j]; o1[j] = (__bf16)src[8 + j]; }
    size_t base = (size_t)(blockIdx.x * 64 + row) * 512 + nbase + seg * 16;
    *(bf16x8*)(PQ + base) = o0;
    *(bf16x8*)(PQ + base + 8) = o1;
  }
}

// ---------- kernel 2: fused span head — 8 waves, one batch/block, k-major LDS ----------
// LDS: h[kc2=k/8][span ^ (kc2&7)][8 bf16]   (32 pages x 1KB; sc reuses identically)
__global__ __launch_bounds__(512, 4) void k2_main(
    const __bf16* __restrict__ PQ, const int* __restrict__ starts, const int* __restrict__ ends,
    const __bf16* __restrict__ WTB, const __bf16* __restrict__ WT, const __bf16* __restrict__ GT,
    const float* __restrict__ bsc, const float* __restrict__ gbv,
    float* __restrict__ outS, float* __restrict__ outL) {
  __shared__ __align__(16) unsigned char h_lds[32768];
  const int tile = blockIdx.x, b = blockIdx.y;
  const int tid = threadIdx.x;
  const int w = tid >> 6, lane = tid & 63, llo = lane & 15, lhi = lane >> 4;

  // ---- stage 1: h = relu(P[s]+Q[e]) + width[e-s] -> k-major LDS ----
  {
    const int rowbase = tid >> 5;  // 0..15 (span = i*16 + rowbase)
    const int ch = tid & 31;       // kc2 page = ch; k-cols = ch*8..+8
    const __bf16* PQb = PQ + (size_t)b * (S_ * 512);
    int sv[4], ev[4];
#pragma unroll
    for (int i = 0; i < 4; i++) {
      int span = min(tile * 64 + i * 16 + rowbase, NSPANS - 1);  // tail: real span, masked at store
      sv[i] = starts[span];
      ev[i] = ends[span];
    }
    bf16x8 pv[4], qv[4], wv[4];
#pragma unroll
    for (int i = 0; i < 4; i++) {
      pv[i] = *(const bf16x8*)(PQb + sv[i] * 512 + ch * 8);
      qv[i] = *(const bf16x8*)(PQb + ev[i] * 512 + 256 + ch * 8);
      wv[i] = *(const bf16x8*)(WTB + (ev[i] - sv[i]) * 256 + ch * 8);
    }
    // write: addr = ch*1024 + ((i*16+rowbase) ^ (ch&7))*16 = base1 + i*256
    unsigned char* wp = h_lds + (unsigned)ch * 1024u + (unsigned)((rowbase ^ (ch & 7)) << 4);
#pragma unroll
    for (int i = 0; i < 4; i++) {
      bf16x8 hv;
#pragma unroll
      for (int j = 0; j < 8; j++)
        hv[j] = (__bf16)(fmaxf((float)pv[i][j] + (float)qv[i][j], 0.f) + (float)wv[i][j]);
      *(bf16x8*)(wp + i * 256) = hv;
    }
  }
  __syncthreads();  // B1: h visible

  // ---- stage 2: D1^T[scCol][span] = sum_k Wsc[k][scCol]*h[span][k]; wave w: cols [32w,32w+32)
  // lane reads h[span = tn*16+llo][k = ks*32 + lhi*8 + 0..7] -> page ks*4+lhi
  // addr = ks*4096 + lhi*1024 + tn*256 + ((llo^lhi) ^ 4*(ks&1))*16 -> 2 bases + imm
  const unsigned char* hbE = h_lds + (unsigned)(lhi * 1024 + ((llo ^ lhi) << 4));
  const unsigned char* hbO = h_lds + (unsigned)(lhi * 1024 + (((llo ^ lhi) ^ 4) << 4));
  float4_ acc[2][4];
#pragma unroll
  for (int tm = 0; tm < 2; tm++)
#pragma unroll
    for (int tn = 0; tn < 4; tn++) acc[tm][tn] = (float4_){0.f, 0.f, 0.f, 0.f};
#pragma unroll
  for (int ks = 0; ks < 8; ++ks) {
    const unsigned char* hp = (ks & 1) ? hbO : hbE;  // static after unroll
    bf16x8 af[2], bfr[4];
#pragma unroll
    for (int tm = 0; tm < 2; tm++)
      af[tm] = *(const bf16x8*)(WT + ((ks * 4 + lhi) * 256 + w * 32 + tm * 16 + llo) * 8);
#pragma unroll
    for (int tn = 0; tn < 4; tn++)
      bfr[tn] = *(const bf16x8*)(hp + tn * 256 + ks * 4096);
#pragma unroll
    for (int tm = 0; tm < 2; tm++)
#pragma unroll
      for (int tn = 0; tn < 4; tn++) acc[tm][tn] = MFMA16(af[tm], bfr[tn], acc[tm][tn]);
  }
  __syncthreads();  // B2: all h reads done before overwriting LDS with sc

  // epilogue: sc = relu(acc + bsc) -> k-major LDS (reuse h_lds)
  // lane writes sc[scCol0 = w*32+tm*16+lhi*4 .. +3][span = tn*16+llo]
  // page kc2s = w*4+tm*2+(lhi>>1); addr = kc2s*1024 + ((span^(kc2s&7))<<4) + (lhi&1)*8
#pragma unroll
  for (int tm = 0; tm < 2; tm++) {
    const int kc2s = w * 4 + tm * 2 + (lhi >> 1);
    float4_ bq = *(const float4_*)(bsc + w * 32 + tm * 16 + lhi * 4);
    unsigned char* ep =
        h_lds + (unsigned)kc2s * 1024u + (unsigned)((llo ^ (kc2s & 7)) << 4) + (unsigned)((lhi & 1) << 3);
#pragma unroll
    for (int tn = 0; tn < 4; tn++) {
      bf16x4 x;
#pragma unroll
      for (int r = 0; r < 4; r++) x[r] = (__bf16)fmaxf(acc[tm][tn][r] + bq[r], 0.f);
      *(bf16x4*)(ep + tn * 256) = x;
    }
  }
  __syncthreads();  // B3: sc visible

  // ---- stage 3: D2^T[gcol][span] = sum_k G[k][gcol]*sc[span][k]; waves 0-3, 16 rows each
  if (w < 4) {
    const unsigned char* sbE = h_lds + (unsigned)(lhi * 1024 + w * 256 + ((llo ^ lhi) << 4));
    const unsigned char* sbO = h_lds + (unsigned)(lhi * 1024 + w * 256 + (((llo ^ lhi) ^ 4) << 4));
    float4_ a2 = (float4_){0.f, 0.f, 0.f, 0.f};
#pragma unroll
    for (int ks = 0; ks < 8; ++ks) {
      const unsigned char* sp = (ks & 1) ? sbO : sbE;
      bf16x8 ga = *(const bf16x8*)(GT + ((ks * 4 + lhi) * 16 + llo) * 8);
      bf16x8 sb = *(const bf16x8*)(sp + ks * 4096);
      a2 = MFMA16(ga, sb, a2);
    }
    const int span2 = tile * 64 + w * 16 + llo;
    if (span2 < NSPANS) {
      const float4_ gq = *(const float4_*)(gbv + lhi * 4);
      size_t base = (size_t)b * NSPANS + span2;
#pragma unroll
      for (int r = 0; r < 4; r++) {
        float v = a2[r] + gq[r];
        int gcol = lhi * 4 + r;
        if (gcol == 0) outS[base] = v;           // span_scores (B,N)
        else outL[base * 15 + (gcol - 1)] = v;   // type_logits (B,N,15)
      }
    }
  }
}

extern "C" void kernel_launch(void* const* d_in, const int* in_sizes, int n_in,
                              void* d_out, int out_size, void* d_ws, size_t ws_size,
                              hipStream_t stream) {
  if (ws_size < (size_t)WS_NEED) return;  // need ~5.0 MB scratch
  const float* E = (const float*)d_in[0];
  const float* Wenc = (const float*)d_in[1];
  const float* benc = (const float*)d_in[2];
  const float* wtab = (const float*)d_in[3];
  const float* Ws1 = (const float*)d_in[4];
  const float* bs1 = (const float*)d_in[5];
  const float* Ws2 = (const float*)d_in[6];
  const float* bs2 = (const float*)d_in[7];
  const float* Wc1 = (const float*)d_in[8];
  const float* bc1 = (const float*)d_in[9];
  const float* Wc2 = (const float*)d_in[10];
  const float* bc2 = (const float*)d_in[11];

  unsigned char* ws = (unsigned char*)d_ws;
  int* starts = (int*)(ws + WS_STARTS);
  int* ends = (int*)(ws + WS_ENDS);
  __bf16* WencP = (__bf16*)(ws + WS_WENCP);
  __bf16* WT = (__bf16*)(ws + WS_WT);
  __bf16* GT = (__bf16*)(ws + WS_GT);
  float* bsc = (float*)(ws + WS_BSC);
  float* gbv = (float*)(ws + WS_GB);
  __bf16* WTB = (__bf16*)(ws + WS_WTB);
  __bf16* PQ = (__bf16*)(ws + WS_PQ);

  float* outS = (float*)d_out;
  float* outL = outS + (size_t)B_ * NSPANS;

  k0_pack<<<dim3(1142), dim3(256), 0, stream>>>(Wenc, Ws1, Wc1, Ws2, Wc2, bs1, bc1, bs2, bc2,
                                                wtab, WencP, WT, GT, bsc, gbv, WTB, starts, ends);
  k1_pq<<<dim3(64, 8), dim3(256), 0, stream>>>(E, WencP, benc, PQ);
  k2_main<<<dim3(NTILES, B_), dim3(512), 0, stream>>>(PQ, starts, ends, WTB, WT, GT, bsc, gbv,
                                                      outS, outL);
}